// Round 10
// baseline (380.871 us; speedup 1.0000x reference)
//
#include <hip/hip_runtime.h>
#include <hip/hip_fp16.h>
#include <math.h>

#define N_NODES 50000
#define N_EDGES 600000
#define D_IN    128
#define D_HID   256
#define D_OUT   128

// src-chunk bucketing for L2 cache-blocking of the gathers
#define CSH   11                          // chunk = 2048 source nodes
#define NCH   ((N_NODES + (1 << CSH) - 1) >> CSH)   // 25
#define NBINS (N_NODES * NCH)             // 1,250,000
#define NB1   ((NBINS + 255) / 256)       // 4883

typedef unsigned short u16;
typedef __attribute__((ext_vector_type(8))) _Float16 f16x8;
typedef __attribute__((ext_vector_type(4))) float f32x4;

__device__ __forceinline__ u16 f2h(float x) {
    __half h = __float2half_rn(x);
    return *reinterpret_cast<u16*>(&h);
}
__device__ __forceinline__ float h2f(u16 h) {
    __half hh = *reinterpret_cast<__half*>(&h);
    return __half2float(hh);
}
__device__ __forceinline__ float2 h2f2(unsigned int raw) {
    __half2 h = *reinterpret_cast<__half2*>(&raw);
    return __half22float2(h);
}

// ---------------------------------------------------------------------------
// Setup chain. Bins = (dst, src-chunk): edge lists come out chunk-sorted per
// node, giving temporal L2 locality in the gather kernels. One atomic/edge,
// nearly contention-free (600K edges over 1.25M bins).
// ---------------------------------------------------------------------------

__global__ void k_hist(const int* __restrict__ src, const int* __restrict__ dst,
                       const float* __restrict__ w, float* __restrict__ ew,
                       int* __restrict__ rank, int* __restrict__ cnt2) {
    int e = blockIdx.x * blockDim.x + threadIdx.x;
    if (e >= N_EDGES) return;
    float x = w[e];
    ew[e] = fmaxf(x, 0.f) + log1pf(expf(-fabsf(x)));
    int key = dst[e] * NCH + (src[e] >> CSH);
    rank[e] = atomicAdd(&cnt2[key], 1);
}

__global__ void k_scan1(const int* __restrict__ cnt2, int* __restrict__ rowptr2,
                        int* __restrict__ bsum) {
    __shared__ int s[256];
    int b = blockIdx.x, t = threadIdx.x;
    int i = b * 256 + t;
    int v = (i < NBINS) ? cnt2[i] : 0;
    s[t] = v;
    __syncthreads();
    for (int off = 1; off < 256; off <<= 1) {
        int u = (t >= off) ? s[t - off] : 0;
        __syncthreads();
        s[t] += u;
        __syncthreads();
    }
    if (i < NBINS) rowptr2[i] = s[t] - v;   // block-local exclusive
    if (t == 255) bsum[b] = s[255];
}

// single block, loops over NB1 partials with running carry
__global__ void k_scan2(const int* __restrict__ bsum, int* __restrict__ boff) {
    __shared__ int s[256];
    __shared__ int carry;
    int t = threadIdx.x;
    if (t == 0) carry = 0;
    __syncthreads();
    for (int base = 0; base < NB1; base += 256) {
        int i = base + t;
        int v = (i < NB1) ? bsum[i] : 0;
        s[t] = v;
        __syncthreads();
        for (int off = 1; off < 256; off <<= 1) {
            int u = (t >= off) ? s[t - off] : 0;
            __syncthreads();
            s[t] += u;
            __syncthreads();
        }
        if (i < NB1) boff[i] = carry + s[t] - v;
        __syncthreads();
        if (t == 255) carry += s[255];
        __syncthreads();
    }
    if (t == 0) boff[NB1] = carry;   // grand total = N_EDGES
}

__global__ void k_scan3(int* __restrict__ rowptr2, const int* __restrict__ boff,
                        int* __restrict__ rowptr) {
    int b = blockIdx.x, t = threadIdx.x;
    int i = b * 256 + t;
    if (i < NBINS) {
        int v = rowptr2[i] + boff[b];
        rowptr2[i] = v;
        if (i % NCH == 0) rowptr[i / NCH] = v;   // node-level rowptr
    }
    if (i == 0) rowptr[N_NODES] = boff[NB1];
}

__global__ void k_fill2(const int* __restrict__ src, const int* __restrict__ dst,
                        const float* __restrict__ ew, const int* __restrict__ rank,
                        const int* __restrict__ rowptr2, int2* __restrict__ ecsr) {
    int e = blockIdx.x * blockDim.x + threadIdx.x;
    if (e >= N_EDGES) return;
    int s = src[e];
    int key = dst[e] * NCH + (s >> CSH);
    int pos = rowptr2[key] + rank[e];
    ecsr[pos] = make_int2(s, __float_as_int(ew[e]));
}

__global__ void k_degdinv(const int* __restrict__ rowptr, const int2* __restrict__ ecsr,
                          float* __restrict__ dinv) {
    int n = blockIdx.x * blockDim.x + threadIdx.x;
    if (n >= N_NODES) return;
    int beg = rowptr[n], end = rowptr[n + 1];
    float s = 1.0f;  // self-loop weight
    for (int p = beg; p < end; p++) s += __int_as_float(ecsr[p].y);
    dinv[n] = rsqrtf(s);
}

__global__ void k_norm(const int* __restrict__ rowptr, const float* __restrict__ dinv,
                       int2* __restrict__ ecsr) {
    int n = blockIdx.x * blockDim.x + threadIdx.x;
    if (n >= N_NODES) return;
    int beg = rowptr[n], end = rowptr[n + 1];
    float dn = dinv[n];
    for (int p = beg; p < end; p++) {
        int2 r = ecsr[p];
        float w = dinv[r.x] * __int_as_float(r.y) * dn;
        ecsr[p] = make_int2(r.x, __float_as_int(w));
    }
}

// ---------------------------------------------------------------------------
// Weight prep: W[K,N] f32 -> Wt[N, 2K] fp16 (hi plane 0..K-1, lo plane K..2K-1)
// ---------------------------------------------------------------------------

#define WPREP_TOTAL 131072

__global__ void k_wprep(const float* __restrict__ W1, const float* __restrict__ W2,
                        const float* __restrict__ W3,
                        u16* __restrict__ B1, u16* __restrict__ B2, u16* __restrict__ B3) {
    int idx = blockIdx.x * blockDim.x + threadIdx.x;
    const float* W; u16* B; int K, N, base;
    if (idx < 32768)       { W = W1; B = B1; K = 128; N = 256; base = 0; }
    else if (idx < 98304)  { W = W2; B = B2; K = 256; N = 256; base = 32768; }
    else if (idx < 131072) { W = W3; B = B3; K = 256; N = 128; base = 98304; }
    else return;
    int p = idx - base;
    int n = p % N, k = p / N;
    float x = W[(size_t)k * N + n];
    u16 hi = f2h(x);
    u16 lo = f2h(x - h2f(hi));
    B[(size_t)n * (2 * K) + k] = hi;
    B[(size_t)n * (2 * K) + K + k] = lo;
}

// ---------------------------------------------------------------------------
// Aggregation (unchanged from R9). INF: 0 = f32 rows, 1 = fp16 rows.
// OUTM: 0 = f32 (+bias), 1 = fp16 [N, D]. One wave per node.
// ---------------------------------------------------------------------------

template <int D, int INF, int OUTM, bool BIAS>
__global__ __launch_bounds__(256) void k_agg(const void* __restrict__ inv,
                                             const int* __restrict__ rowptr,
                                             const int2* __restrict__ ecsr,
                                             const float* __restrict__ dinv,
                                             const float* __restrict__ bias,
                                             void* __restrict__ outv) {
    int node = blockIdx.x * 4 + (threadIdx.x >> 6);
    int lane = threadIdx.x & 63;
    if (node >= N_NODES) return;
    float dn = dinv[node];
    float dd = dn * dn;
    int beg = rowptr[node], end = rowptr[node + 1];

    if (D == 256) {
        const float* inf = (const float*)inv;
        const u16* inh = (const u16*)inv;
        float sx, sy, sz, sw;
        if (INF == 0) {
            float4 sv = *(reinterpret_cast<const float4*>(inf + (size_t)node * D) + lane);
            sx = sv.x; sy = sv.y; sz = sv.z; sw = sv.w;
        } else {
            uint2 raw = *reinterpret_cast<const uint2*>(inh + (size_t)node * D + lane * 4);
            float2 f01 = h2f2(raw.x), f23 = h2f2(raw.y);
            sx = f01.x; sy = f01.y; sz = f23.x; sw = f23.y;
        }
        float ax = dd * sx, ay = dd * sy, az = dd * sz, aw = dd * sw;
        int p = beg;
        for (; p + 4 <= end; p += 4) {
            int2 e0 = ecsr[p], e1 = ecsr[p + 1], e2 = ecsr[p + 2], e3 = ecsr[p + 3];
            float w0 = __int_as_float(e0.y), w1 = __int_as_float(e1.y);
            float w2 = __int_as_float(e2.y), w3 = __int_as_float(e3.y);
            if (INF == 0) {
                float4 r0 = *(reinterpret_cast<const float4*>(inf + (size_t)e0.x * D) + lane);
                float4 r1 = *(reinterpret_cast<const float4*>(inf + (size_t)e1.x * D) + lane);
                float4 r2 = *(reinterpret_cast<const float4*>(inf + (size_t)e2.x * D) + lane);
                float4 r3 = *(reinterpret_cast<const float4*>(inf + (size_t)e3.x * D) + lane);
                ax += w0 * r0.x; ay += w0 * r0.y; az += w0 * r0.z; aw += w0 * r0.w;
                ax += w1 * r1.x; ay += w1 * r1.y; az += w1 * r1.z; aw += w1 * r1.w;
                ax += w2 * r2.x; ay += w2 * r2.y; az += w2 * r2.z; aw += w2 * r2.w;
                ax += w3 * r3.x; ay += w3 * r3.y; az += w3 * r3.z; aw += w3 * r3.w;
            } else {
                uint2 q0 = *reinterpret_cast<const uint2*>(inh + (size_t)e0.x * D + lane * 4);
                uint2 q1 = *reinterpret_cast<const uint2*>(inh + (size_t)e1.x * D + lane * 4);
                uint2 q2 = *reinterpret_cast<const uint2*>(inh + (size_t)e2.x * D + lane * 4);
                uint2 q3 = *reinterpret_cast<const uint2*>(inh + (size_t)e3.x * D + lane * 4);
                float2 a0 = h2f2(q0.x), b0 = h2f2(q0.y);
                float2 a1 = h2f2(q1.x), b1 = h2f2(q1.y);
                float2 a2 = h2f2(q2.x), b2 = h2f2(q2.y);
                float2 a3 = h2f2(q3.x), b3 = h2f2(q3.y);
                ax += w0 * a0.x; ay += w0 * a0.y; az += w0 * b0.x; aw += w0 * b0.y;
                ax += w1 * a1.x; ay += w1 * a1.y; az += w1 * b1.x; aw += w1 * b1.y;
                ax += w2 * a2.x; ay += w2 * a2.y; az += w2 * b2.x; aw += w2 * b2.y;
                ax += w3 * a3.x; ay += w3 * a3.y; az += w3 * b3.x; aw += w3 * b3.y;
            }
        }
        for (; p < end; p++) {
            int2 e0 = ecsr[p];
            float w0 = __int_as_float(e0.y);
            if (INF == 0) {
                float4 r0 = *(reinterpret_cast<const float4*>(inf + (size_t)e0.x * D) + lane);
                ax += w0 * r0.x; ay += w0 * r0.y; az += w0 * r0.z; aw += w0 * r0.w;
            } else {
                uint2 q0 = *reinterpret_cast<const uint2*>(inh + (size_t)e0.x * D + lane * 4);
                float2 a0 = h2f2(q0.x), b0 = h2f2(q0.y);
                ax += w0 * a0.x; ay += w0 * a0.y; az += w0 * b0.x; aw += w0 * b0.y;
            }
        }
        if (OUTM == 0) {
            float* out = (float*)outv;
            if (BIAS) {
                float4 b = *(reinterpret_cast<const float4*>(bias) + lane);
                ax += b.x; ay += b.y; az += b.z; aw += b.w;
            }
            float4 res; res.x = ax; res.y = ay; res.z = az; res.w = aw;
            *(reinterpret_cast<float4*>(out + (size_t)node * D) + lane) = res;
        } else {
            u16* out = (u16*)outv;  // fp16 [N, 256]
            ushort4 hv;
            hv.x = f2h(ax); hv.y = f2h(ay); hv.z = f2h(az); hv.w = f2h(aw);
            *reinterpret_cast<ushort4*>(out + (size_t)node * D + lane * 4) = hv;
        }
    } else {  // D == 128
        const float* inf = (const float*)inv;
        const u16* inh = (const u16*)inv;
        float sx, sy;
        if (INF == 0) {
            float2 sv = *(reinterpret_cast<const float2*>(inf + (size_t)node * D) + lane);
            sx = sv.x; sy = sv.y;
        } else {
            unsigned int raw = *reinterpret_cast<const unsigned int*>(inh + (size_t)node * D + lane * 2);
            float2 f = h2f2(raw);
            sx = f.x; sy = f.y;
        }
        float ax = dd * sx, ay = dd * sy;
        int p = beg;
        for (; p + 4 <= end; p += 4) {
            int2 e0 = ecsr[p], e1 = ecsr[p + 1], e2 = ecsr[p + 2], e3 = ecsr[p + 3];
            float w0 = __int_as_float(e0.y), w1 = __int_as_float(e1.y);
            float w2 = __int_as_float(e2.y), w3 = __int_as_float(e3.y);
            if (INF == 0) {
                float2 r0 = *(reinterpret_cast<const float2*>(inf + (size_t)e0.x * D) + lane);
                float2 r1 = *(reinterpret_cast<const float2*>(inf + (size_t)e1.x * D) + lane);
                float2 r2 = *(reinterpret_cast<const float2*>(inf + (size_t)e2.x * D) + lane);
                float2 r3 = *(reinterpret_cast<const float2*>(inf + (size_t)e3.x * D) + lane);
                ax += w0 * r0.x; ay += w0 * r0.y;
                ax += w1 * r1.x; ay += w1 * r1.y;
                ax += w2 * r2.x; ay += w2 * r2.y;
                ax += w3 * r3.x; ay += w3 * r3.y;
            } else {
                unsigned int q0 = *reinterpret_cast<const unsigned int*>(inh + (size_t)e0.x * D + lane * 2);
                unsigned int q1 = *reinterpret_cast<const unsigned int*>(inh + (size_t)e1.x * D + lane * 2);
                unsigned int q2 = *reinterpret_cast<const unsigned int*>(inh + (size_t)e2.x * D + lane * 2);
                unsigned int q3 = *reinterpret_cast<const unsigned int*>(inh + (size_t)e3.x * D + lane * 2);
                float2 f0 = h2f2(q0), f1 = h2f2(q1), f2 = h2f2(q2), f3 = h2f2(q3);
                ax += w0 * f0.x; ay += w0 * f0.y;
                ax += w1 * f1.x; ay += w1 * f1.y;
                ax += w2 * f2.x; ay += w2 * f2.y;
                ax += w3 * f3.x; ay += w3 * f3.y;
            }
        }
        for (; p < end; p++) {
            int2 e0 = ecsr[p];
            float w0 = __int_as_float(e0.y);
            if (INF == 0) {
                float2 r0 = *(reinterpret_cast<const float2*>(inf + (size_t)e0.x * D) + lane);
                ax += w0 * r0.x; ay += w0 * r0.y;
            } else {
                unsigned int q0 = *reinterpret_cast<const unsigned int*>(inh + (size_t)e0.x * D + lane * 2);
                float2 f0 = h2f2(q0);
                ax += w0 * f0.x; ay += w0 * f0.y;
            }
        }
        if (OUTM == 0) {
            float* out = (float*)outv;
            if (BIAS) {
                float2 b = *(reinterpret_cast<const float2*>(bias) + lane);
                ax += b.x; ay += b.y;
            }
            float2 res; res.x = ax; res.y = ay;
            *(reinterpret_cast<float2*>(out + (size_t)node * D) + lane) = res;
        } else {
            u16* out = (u16*)outv;  // fp16 [N, 128]
            ushort2 hv; hv.x = f2h(ax); hv.y = f2h(ay);
            *reinterpret_cast<ushort2*>(out + (size_t)node * D + lane * 2) = hv;
        }
    }
}

// ---------------------------------------------------------------------------
// fp16 MFMA GEMM with fp16-hilo weights (unchanged from R8).
// ---------------------------------------------------------------------------

template <int OUT, bool BIAS, bool RELU>
__global__ __launch_bounds__(256) void k_gemm_h(const u16* __restrict__ Ap,
                                                const u16* __restrict__ Bp,
                                                const float* __restrict__ bias,
                                                void* __restrict__ Cv,
                                                int M, int K, int NN) {
    const int KP2 = 2 * K;
    __shared__ u16 As[8 * 544];
    __shared__ u16 Bs[2 * 8 * 544];
    int tid = threadIdx.x;
    int bm = blockIdx.y * 128;
    int bn = blockIdx.x * 128;
    int l = tid & 63;
    int w = tid >> 6;
    int wr = w >> 1, wc = w & 1;

    f32x4 zero = {0.f, 0.f, 0.f, 0.f};
    f32x4 acc[4][4];
    #pragma unroll
    for (int i = 0; i < 4; i++)
        #pragma unroll
        for (int j = 0; j < 4; j++) acc[i][j] = zero;

    for (int k0 = 0; k0 < K; k0 += 32) {
        #pragma unroll
        for (int q = 0; q < 2; q++) {
            int idx = tid + q * 256;
            int r = idx >> 2, o = idx & 3;
            int gr = bm + r;
            uint4 va = make_uint4(0u, 0u, 0u, 0u);
            if (gr < M)
                va = *reinterpret_cast<const uint4*>(Ap + (size_t)gr * K + k0 + o * 8);
            *reinterpret_cast<uint4*>(&As[(r >> 4) * 544 + o * 136 + (r & 15) * 8]) = va;
        }
        #pragma unroll
        for (int q = 0; q < 4; q++) {
            int idx = tid + q * 256;
            int r = idx >> 3, oct = idx & 7;
            int hf = oct >> 2, o = oct & 3;
            uint4 vb = *reinterpret_cast<const uint4*>(
                Bp + (size_t)(bn + r) * KP2 + hf * K + k0 + o * 8);
            *reinterpret_cast<uint4*>(
                &Bs[hf * 4352 + (r >> 4) * 544 + o * 136 + (r & 15) * 8]) = vb;
        }
        __syncthreads();
        int fro = (l >> 4) * 136 + (l & 15) * 8;
        f16x8 a[4], bh[4], bl[4];
        #pragma unroll
        for (int i = 0; i < 4; i++)
            a[i] = *reinterpret_cast<const f16x8*>(&As[(wr * 4 + i) * 544 + fro]);
        #pragma unroll
        for (int j = 0; j < 4; j++) {
            bh[j] = *reinterpret_cast<const f16x8*>(&Bs[(wc * 4 + j) * 544 + fro]);
            bl[j] = *reinterpret_cast<const f16x8*>(&Bs[4352 + (wc * 4 + j) * 544 + fro]);
        }
        #pragma unroll
        for (int i = 0; i < 4; i++)
            #pragma unroll
            for (int j = 0; j < 4; j++) {
                acc[i][j] = __builtin_amdgcn_mfma_f32_16x16x32_f16(a[i], bh[j], acc[i][j], 0, 0, 0);
                acc[i][j] = __builtin_amdgcn_mfma_f32_16x16x32_f16(a[i], bl[j], acc[i][j], 0, 0, 0);
            }
        __syncthreads();
    }

    int cl = l & 15;
    int rq = (l >> 4) * 4;
    float bv[4];
    #pragma unroll
    for (int j = 0; j < 4; j++) {
        int gc = bn + wc * 64 + j * 16 + cl;
        bv[j] = BIAS ? bias[gc] : 0.f;
    }
    #pragma unroll
    for (int i = 0; i < 4; i++) {
        #pragma unroll
        for (int r = 0; r < 4; r++) {
            int grow = bm + wr * 64 + i * 16 + rq + r;
            if (grow >= M) continue;
            #pragma unroll
            for (int j = 0; j < 4; j++) {
                int gc = bn + wc * 64 + j * 16 + cl;
                float v = acc[i][j][r];
                if (BIAS) v += bv[j];
                if (RELU) v = fmaxf(v, 0.f);
                if (OUT == 0) {
                    ((float*)Cv)[(size_t)grow * NN + gc] = v;
                } else {
                    ((u16*)Cv)[(size_t)grow * NN + gc] = f2h(v);
                }
            }
        }
    }
}

// ---------------------------------------------------------------------------
// launch
// ---------------------------------------------------------------------------

extern "C" void kernel_launch(void* const* d_in, const int* in_sizes, int n_in,
                              void* d_out, int out_size, void* d_ws, size_t ws_size,
                              hipStream_t stream) {
    const float* x   = (const float*)d_in[0];
    const int*   ei  = (const int*)d_in[1];
    const float* wts = (const float*)d_in[2];
    const float* W1  = (const float*)d_in[3];
    const float* b1  = (const float*)d_in[4];
    const float* W2  = (const float*)d_in[5];
    const float* b2  = (const float*)d_in[6];
    const float* W3  = (const float*)d_in[7];
    const float* b3  = (const float*)d_in[8];
    float* out = (float*)d_out;
    const int* src = ei;
    const int* dst = ei + N_EDGES;

    float* bufA    = (float*)d_ws;                        // fp16 [N,256] max
    float* bufB    = bufA + (size_t)N_NODES * D_HID;      // fp16 [N,256] max
    float* ew      = bufB + (size_t)N_NODES * D_HID;      // [E]
    float* dinv    = ew + N_EDGES;                        // [N]
    int*   rank    = (int*)(dinv + N_NODES);              // [E]
    int*   rowptr  = rank + N_EDGES;                      // [N+2]
    int2*  ecsr    = (int2*)(rowptr + (N_NODES + 2));     // [E] packed {src, w}
    u16*   Wb1     = (u16*)(ecsr + N_EDGES);              // [256*256]
    u16*   Wb2     = Wb1 + 256 * 256;                     // [256*512]
    u16*   Wb3     = Wb2 + 256 * 512;                     // [128*512]
    int*   cnt2    = (int*)(Wb3 + 128 * 512);             // [NBINS]
    int*   rowptr2 = cnt2 + NBINS;                        // [NBINS+1]
    int*   bsum    = rowptr2 + NBINS + 2;                 // [NB1]
    int*   boff    = bsum + NB1;                          // [NB1+1]

    hipMemsetAsync(cnt2, 0, sizeof(int) * NBINS, stream);

    int ethreads = 256;
    int eblocks = (N_EDGES + ethreads - 1) / ethreads;
    int nblocks = (N_NODES + 255) / 256;
    k_hist<<<eblocks, ethreads, 0, stream>>>(src, dst, wts, ew, rank, cnt2);
    k_scan1<<<NB1, 256, 0, stream>>>(cnt2, rowptr2, bsum);
    k_scan2<<<1, 256, 0, stream>>>(bsum, boff);
    k_scan3<<<NB1, 256, 0, stream>>>(rowptr2, boff, rowptr);
    k_fill2<<<eblocks, ethreads, 0, stream>>>(src, dst, ew, rank, rowptr2, ecsr);
    k_degdinv<<<nblocks, 256, 0, stream>>>(rowptr, ecsr, dinv);
    k_norm<<<nblocks, 256, 0, stream>>>(rowptr, dinv, ecsr);
    k_wprep<<<(WPREP_TOTAL + 255) / 256, 256, 0, stream>>>(W1, W2, W3, Wb1, Wb2, Wb3);

    int aggBlocks = (N_NODES + 3) / 4;
    int gy = (N_NODES + 127) / 128;  // 391

    // agg1: x (f32) -> bufA fp16 [N,128]
    k_agg<128, 0, 1, false><<<aggBlocks, 256, 0, stream>>>(x, rowptr, ecsr, dinv, nullptr, bufA);
    // gemm1: h1 = relu(bufA @ W1 + b1) -> bufB fp16 [N,256]
    {
        dim3 g(2, gy);
        k_gemm_h<1, true, true><<<g, 256, 0, stream>>>((const u16*)bufA, Wb1, b1, bufB,
                                                       N_NODES, D_IN, D_HID);
    }
    // agg2: bufB fp16 -> bufA fp16 [N,256]
    k_agg<256, 1, 1, false><<<aggBlocks, 256, 0, stream>>>(bufB, rowptr, ecsr, dinv, nullptr, bufA);
    // gemm2: h2 = relu(bufA @ W2 + b2) -> bufB fp16 [N,256]
    {
        dim3 g(2, gy);
        k_gemm_h<1, true, true><<<g, 256, 0, stream>>>((const u16*)bufA, Wb2, b2, bufB,
                                                       N_NODES, D_HID, D_HID);
    }
    // gemm3: y3 = bufB @ W3 -> bufA fp16 [N,128]
    {
        dim3 g(1, gy);
        k_gemm_h<1, false, false><<<g, 256, 0, stream>>>((const u16*)bufB, Wb3, nullptr, bufA,
                                                         N_NODES, D_HID, D_OUT);
    }
    // agg3: bufA fp16 -> out f32 + b3
    k_agg<128, 1, 0, true><<<aggBlocks, 256, 0, stream>>>(bufA, rowptr, ecsr, dinv, b3, out);
}